// Round 2
// baseline (636.900 us; speedup 1.0000x reference)
//
#include <hip/hip_runtime.h>
#include <stdint.h>

typedef __attribute__((ext_vector_type(8))) short bf16x8;
typedef __attribute__((ext_vector_type(4))) float f32x4;
typedef __attribute__((ext_vector_type(4))) unsigned int u32x4;
typedef __attribute__((ext_vector_type(4))) unsigned short u16x4;

typedef const void __attribute__((address_space(1))) gvoid_t;
typedef void __attribute__((address_space(3))) lvoid_t;

__device__ __forceinline__ unsigned short f2bf(float f) {
  union { float f; unsigned int u; } v; v.f = f;
  unsigned int u = v.u;
  u += 0x7fffu + ((u >> 16) & 1u);
  return (unsigned short)(u >> 16);
}
__device__ __forceinline__ float bf2f(unsigned short h) {
  union { unsigned int u; float f; } v; v.u = ((unsigned int)h) << 16;
  return v.f;
}
__device__ __forceinline__ void load_lds16(const void* g, void* l) {
  __builtin_amdgcn_global_load_lds((gvoid_t*)g, (lvoid_t*)l, 16, 0, 0);
}

// ---------------- weight f32 -> bf16 ----------------
__global__ __launch_bounds__(256) void k_cvt(const float* __restrict__ src,
                                             unsigned short* __restrict__ dst, int n) {
  int i = blockIdx.x * 256 + threadIdx.x;
  if (i < n) dst[i] = f2bf(src[i]);
}

// ---------------- gather + LN1 -> xn bf16 [rows][512] (chunk-local) ----------------
__global__ __launch_bounds__(256) void k_gather_ln(const int* __restrict__ conn,
                                                   const float* __restrict__ emb,
                                                   const float* __restrict__ g1,
                                                   const float* __restrict__ b1,
                                                   unsigned short* __restrict__ xn,
                                                   int row0) {
  const int lane = threadIdx.x & 63;
  const int wid = threadIdx.x >> 6;
  const int rloc = blockIdx.x * 4 + wid;
  const int row = row0 + rloc;
  const int rel = conn[row * 2 + 0];
  const int ent = conn[row * 2 + 1];
  const float4 r4 = *(const float4*)(emb + (size_t)rel * 256 + lane * 4);
  const float4 e4 = *(const float4*)(emb + (size_t)ent * 256 + lane * 4);
  float rv[4] = {r4.x, r4.y, r4.z, r4.w};
  float ev[4] = {e4.x, e4.y, e4.z, e4.w};
  float s = 0.f, ss = 0.f;
#pragma unroll
  for (int j = 0; j < 4; ++j) { s += rv[j] + ev[j]; ss += rv[j] * rv[j] + ev[j] * ev[j]; }
#pragma unroll
  for (int d = 1; d < 64; d <<= 1) { s += __shfl_xor(s, d, 64); ss += __shfl_xor(ss, d, 64); }
  const float mu = s * (1.f / 512.f);
  const float var = ss * (1.f / 512.f) - mu * mu;
  const float rs = rsqrtf(var + 1e-5f);
  const float4 ga = *(const float4*)(g1 + lane * 4);
  const float4 gb = *(const float4*)(g1 + 256 + lane * 4);
  const float4 ba = *(const float4*)(b1 + lane * 4);
  const float4 bb = *(const float4*)(b1 + 256 + lane * 4);
  float gav[4] = {ga.x, ga.y, ga.z, ga.w}, gbv[4] = {gb.x, gb.y, gb.z, gb.w};
  float bav[4] = {ba.x, ba.y, ba.z, ba.w}, bbv[4] = {bb.x, bb.y, bb.z, bb.w};
  u16x4 o0, o1;
#pragma unroll
  for (int j = 0; j < 4; ++j) {
    o0[j] = f2bf((rv[j] - mu) * rs * gav[j] + bav[j]);
    o1[j] = f2bf((ev[j] - mu) * rs * gbv[j] + bbv[j]);
  }
  unsigned short* orow = xn + (size_t)rloc * 512;
  *(u16x4*)(orow + lane * 4) = o0;
  *(u16x4*)(orow + 256 + lane * 4) = o1;
}

// ---------------- GEMM: C[M,N] = A[M,K] * W[N,K]^T + bias, bf16 in/out, f32 acc ----
__global__ __launch_bounds__(256) void k_gemm(const unsigned short* __restrict__ A,
                                              const unsigned short* __restrict__ W,
                                              const float* __restrict__ bias,
                                              unsigned short* __restrict__ C,
                                              int N, int K) {
  __shared__ __align__(16) unsigned short ldsA[2][128 * 32];
  __shared__ __align__(16) unsigned short ldsB[2][128 * 32];
  const int t = threadIdx.x;
  const int lane = t & 63;
  const int wid = t >> 6;
  const int wm = wid >> 1, wn = wid & 1;
  const int mtile = blockIdx.y, ntile = blockIdx.x;
  const size_t Abase = (size_t)mtile * 128 * K;
  const size_t Wbase = (size_t)ntile * 128 * K;
  const int NT = K >> 5;

  f32x4 acc[4][4];
#pragma unroll
  for (int i = 0; i < 4; ++i)
#pragma unroll
    for (int j = 0; j < 4; ++j) acc[i][j] = (f32x4){0.f, 0.f, 0.f, 0.f};

  auto stage = [&](int buf, int kt) {
#pragma unroll
    for (int it = 0; it < 2; ++it) {
      int row = it * 64 + (t >> 2);
      int cl = (t & 3) ^ ((row >> 1) & 3);
      load_lds16(A + Abase + (size_t)row * K + kt * 32 + cl * 8, &ldsA[buf][it * 2048 + t * 8]);
    }
#pragma unroll
    for (int it = 0; it < 2; ++it) {
      int row = it * 64 + (t >> 2);
      int cl = (t & 3) ^ ((row >> 1) & 3);
      load_lds16(W + Wbase + (size_t)row * K + kt * 32 + cl * 8, &ldsB[buf][it * 2048 + t * 8]);
    }
  };

  stage(0, 0);
  __syncthreads();

  for (int kt = 0; kt < NT; ++kt) {
    const int cur = kt & 1;
    if (kt + 1 < NT) stage(cur ^ 1, kt + 1);
    bf16x8 af[4], bfr[4];
#pragma unroll
    for (int mi = 0; mi < 4; ++mi) {
      int row = wm * 64 + mi * 16 + (lane & 15);
      int st = (lane >> 4) ^ ((row >> 1) & 3);
      af[mi] = *(const bf16x8*)&ldsA[cur][row * 32 + st * 8];
    }
#pragma unroll
    for (int ni = 0; ni < 4; ++ni) {
      int row = wn * 64 + ni * 16 + (lane & 15);
      int st = (lane >> 4) ^ ((row >> 1) & 3);
      bfr[ni] = *(const bf16x8*)&ldsB[cur][row * 32 + st * 8];
    }
#pragma unroll
    for (int mi = 0; mi < 4; ++mi)
#pragma unroll
      for (int ni = 0; ni < 4; ++ni)
        acc[mi][ni] = __builtin_amdgcn_mfma_f32_16x16x32_bf16(af[mi], bfr[ni], acc[mi][ni], 0, 0, 0);
    __syncthreads();
  }

#pragma unroll
  for (int ni = 0; ni < 4; ++ni) {
    const int col = ntile * 128 + wn * 64 + ni * 16 + (lane & 15);
    const float bv = bias[col];
#pragma unroll
    for (int mi = 0; mi < 4; ++mi) {
      const int row0 = mtile * 128 + wm * 64 + mi * 16 + ((lane >> 4) << 2);
#pragma unroll
      for (int r = 0; r < 4; ++r)
        C[(size_t)(row0 + r) * N + col] = f2bf(acc[mi][ni][r] + bv);
    }
  }
}

// ---------------- fused attention per (b,h), 62KB static LDS ----------------
__global__ __launch_bounds__(512) void k_attn(const unsigned short* __restrict__ qkv,
                                              const int* __restrict__ mask,
                                              unsigned short* __restrict__ y,
                                              float* __restrict__ am, int b0) {
  __shared__ __align__(16) unsigned short A_lds[128 * 128];   // K, then V^T
  __shared__ __align__(16) unsigned short P_lds[7 * 16 * 128];
  __shared__ float am_s[112];
  const int t = threadIdx.x, lane = t & 63, w = t >> 6;
  const int bl = blockIdx.x >> 2, h = blockIdx.x & 3;
  const int bg = b0 + bl;
  const unsigned short* qk = qkv + (size_t)bl * 153600;  // 100*1536, chunk-local

  if (t < 112) am_s[t] = 0.f;

  // ---- stage K rows 0..99 (src-swizzled, linear LDS dest) ----
#pragma unroll
  for (int j = 0; j < 4; ++j) {
    const int row = j * 32 + w * 4 + (lane >> 4);
    if (row < 100) {  // wave-uniform: rows per (j,w) are a 4-aligned group
      const int c = (lane & 15) ^ (row & 7);
      load_lds16(qk + (size_t)row * 1536 + 512 + h * 128 + c * 8,
                 &A_lds[j * 4096 + w * 512 + lane * 8]);
    }
  }
  // ---- V rows -> regs (contiguous 16B) ----
  u32x4 vv[4];
#pragma unroll
  for (int p = 0; p < 4; ++p) {
    const int vm = p * 32 + (t >> 4);
    const u32x4 z = {0u, 0u, 0u, 0u};
    vv[p] = (vm < 100) ? *(const u32x4*)(qk + (size_t)vm * 1536 + 1024 + h * 128 + (t & 15) * 8) : z;
  }
  // ---- Q fragments -> regs ----
  bf16x8 qf[4];
  {
    const int qrow = w * 16 + (lane & 15);
    const bool qv = (w < 7) && (qrow < 100);
#pragma unroll
    for (int kk = 0; kk < 4; ++kk) {
      const bf16x8 z = {0, 0, 0, 0, 0, 0, 0, 0};
      qf[kk] = qv ? *(const bf16x8*)(qk + (size_t)qrow * 1536 + h * 128 + kk * 32 + (lane >> 4) * 8) : z;
    }
  }
  // zero K pad rows 100..111 (their LDS slots were skipped above)
  if (t < 192) {
    const u32x4 z = {0u, 0u, 0u, 0u};
    *(u32x4*)&A_lds[(100 + (t >> 4)) * 128 + (t & 15) * 8] = z;
  }
  __syncthreads();

  // ---- S = Q K^T ----
  f32x4 sa[7];
#pragma unroll
  for (int ni = 0; ni < 7; ++ni) sa[ni] = (f32x4){0.f, 0.f, 0.f, 0.f};
  if (w < 7) {
#pragma unroll
    for (int kk = 0; kk < 4; ++kk)
#pragma unroll
      for (int ni = 0; ni < 7; ++ni) {
        const int row = ni * 16 + (lane & 15);
        const int c = (kk * 4 + (lane >> 4)) ^ (row & 7);
        const bf16x8 kf = *(const bf16x8*)&A_lds[row * 128 + (c << 3)];
        sa[ni] = __builtin_amdgcn_mfma_f32_16x16x32_bf16(qf[kk], kf, sa[ni], 0, 0, 0);
      }
  }
  __syncthreads();

  // ---- V^T into A_lds (hash ((d>>3)^d)&7 keeps both sides ~2-way) ----
#pragma unroll
  for (int p = 0; p < 4; ++p) {
    const int vm = p * 32 + (t >> 4);
    unsigned short tmp[8];
    *(u32x4*)tmp = vv[p];
#pragma unroll
    for (int jj = 0; jj < 8; ++jj) {
      const int d = (lane & 15) * 8 + jj;
      const int swz = (vm >> 3) ^ (((d >> 3) ^ d) & 7);
      A_lds[d * 128 + swz * 8 + (vm & 7)] = tmp[jj];
    }
  }

  // ---- softmax in registers; P -> P_lds; column partials -> am_s ----
  if (w < 7) {
    const float scale = 0.08838834764831843f;
    float psum[7] = {0.f, 0.f, 0.f, 0.f, 0.f, 0.f, 0.f};
#pragma unroll
    for (int r = 0; r < 4; ++r) {
      const int lr = (lane >> 4) * 4 + r;
      const int qrow = w * 16 + lr;
      if (qrow < 100) {  // uniform within each 16-lane shuffle group
        const int* mrow = mask + ((size_t)bg * 100 + qrow) * 100;
        float x[7];
#pragma unroll
        for (int ni = 0; ni < 7; ++ni) {
          const int col = ni * 16 + (lane & 15);
          x[ni] = (col < 100) ? ((mrow[col] == 0) ? -1e9f : sa[ni][r] * scale) : -1e30f;
        }
        float mx = x[0];
#pragma unroll
        for (int ni = 1; ni < 7; ++ni) mx = fmaxf(mx, x[ni]);
#pragma unroll
        for (int dd = 1; dd < 16; dd <<= 1) mx = fmaxf(mx, __shfl_xor(mx, dd, 64));
        float e[7], sum = 0.f;
#pragma unroll
        for (int ni = 0; ni < 7; ++ni) { e[ni] = __expf(x[ni] - mx); sum += e[ni]; }
#pragma unroll
        for (int dd = 1; dd < 16; dd <<= 1) sum += __shfl_xor(sum, dd, 64);
        const float inv = 1.f / sum;
#pragma unroll
        for (int ni = 0; ni < 7; ++ni) {
          const float pv = e[ni] * inv;
          psum[ni] += pv;
          const int col = ni * 16 + (lane & 15);
          const int c = (col >> 3) ^ (lr & 7);
          P_lds[w * 2048 + lr * 128 + c * 8 + (col & 7)] = f2bf(pv);
        }
      } else {
#pragma unroll
        for (int ni = 0; ni < 7; ++ni) {
          const int col = ni * 16 + (lane & 15);
          const int c = (col >> 3) ^ (lr & 7);
          P_lds[w * 2048 + lr * 128 + c * 8 + (col & 7)] = 0;
        }
      }
    }
    if (lane < 32) {  // zero cols 112..127 (chunks 14,15)
      const int lr = lane & 15;
      const int c = (14 + (lane >> 4)) ^ (lr & 7);
      const u32x4 z = {0u, 0u, 0u, 0u};
      *(u32x4*)&P_lds[w * 2048 + lr * 128 + c * 8] = z;
    }
#pragma unroll
    for (int ni = 0; ni < 7; ++ni) atomicAdd(&am_s[ni * 16 + (lane & 15)], psum[ni]);
  }
  __syncthreads();

  if (t < 100) am[((size_t)bg * 4 + h) * 100 + t] = am_s[t] * 0.01f;

  // ---- y = P V ----
  if (w < 7) {
#pragma unroll
    for (int dt = 0; dt < 8; ++dt) {
      f32x4 acc = {0.f, 0.f, 0.f, 0.f};
#pragma unroll
      for (int kk = 0; kk < 4; ++kk) {
        const int c = kk * 4 + (lane >> 4);
        const bf16x8 pf = *(const bf16x8*)&P_lds[w * 2048 + (lane & 15) * 128 + ((c ^ (lane & 7)) << 3)];
        const int d = dt * 16 + (lane & 15);
        const int cv = c ^ (((d >> 3) ^ d) & 7);
        const bf16x8 vf = *(const bf16x8*)&A_lds[d * 128 + (cv << 3)];
        acc = __builtin_amdgcn_mfma_f32_16x16x32_bf16(pf, vf, acc, 0, 0, 0);
      }
      const int d = dt * 16 + (lane & 15);
#pragma unroll
      for (int r = 0; r < 4; ++r) {
        const int qrow = w * 16 + (lane >> 4) * 4 + r;
        if (qrow < 100)
          y[((size_t)bl * 100 + qrow) * 512 + h * 128 + d] = f2bf(acc[r]);
      }
    }
  }
}

// ---------------- per-b finale: wc = am . yp ; LN2 ; @fc_w^T + fc_b ----------------
__global__ __launch_bounds__(256) void k_final(const float* __restrict__ am,
                                               const unsigned short* __restrict__ yp,
                                               const float* __restrict__ g2,
                                               const float* __restrict__ b2,
                                               const unsigned short* __restrict__ fcw,
                                               const float* __restrict__ fcb,
                                               float* __restrict__ out, int b0) {
  __shared__ float ams[400];
  __shared__ float wcn[4][512];
  const int b = blockIdx.x, t = threadIdx.x;
  const int bg = b0 + b;
  for (int i = t; i < 400; i += 256) ams[i] = am[(size_t)bg * 400 + i];
  __syncthreads();
  float a0[4] = {0, 0, 0, 0}, a1[4] = {0, 0, 0, 0};
  const unsigned short* yb = yp + (size_t)b * 100 * 512 + t * 2;
  for (int n = 0; n < 100; ++n) {
    const unsigned int u = *(const unsigned int*)(yb + n * 512);
    const float v0 = bf2f((unsigned short)(u & 0xffffu));
    const float v1 = bf2f((unsigned short)(u >> 16));
#pragma unroll
    for (int hh = 0; hh < 4; ++hh) {
      const float ww = ams[hh * 100 + n];
      a0[hh] += ww * v0;
      a1[hh] += ww * v1;
    }
  }
#pragma unroll
  for (int hh = 0; hh < 4; ++hh) {
    wcn[hh][2 * t] = a0[hh];
    wcn[hh][2 * t + 1] = a1[hh];
  }
  __syncthreads();
  {
    const int hh = t >> 6, lane = t & 63;
    float vals[8];
    float s = 0.f, ss = 0.f;
#pragma unroll
    for (int j = 0; j < 8; ++j) {
      const float v = wcn[hh][lane * 8 + j];
      vals[j] = v;
      s += v;
      ss += v * v;
    }
#pragma unroll
    for (int d = 1; d < 64; d <<= 1) { s += __shfl_xor(s, d, 64); ss += __shfl_xor(ss, d, 64); }
    const float mu = s * (1.f / 512.f);
    const float var = ss * (1.f / 512.f) - mu * mu;
    const float rs = rsqrtf(var + 1e-5f);
#pragma unroll
    for (int j = 0; j < 8; ++j) {
      const int c = lane * 8 + j;
      wcn[hh][c] = (vals[j] - mu) * rs * g2[c] + b2[c];
    }
  }
  __syncthreads();
  {
    const int o = t;
    float acc[4] = {0, 0, 0, 0};
    const unsigned short* fr = fcw + (size_t)o * 512;
    for (int c0 = 0; c0 < 512; c0 += 8) {
      unsigned short w8[8];
      *(u32x4*)w8 = *(const u32x4*)(fr + c0);
#pragma unroll
      for (int j = 0; j < 8; ++j) {
        const float wv = bf2f(w8[j]);
#pragma unroll
        for (int hh = 0; hh < 4; ++hh) acc[hh] += wv * wcn[hh][c0 + j];
      }
    }
    const float fb = fcb[o];
#pragma unroll
    for (int hh = 0; hh < 4; ++hh) out[(size_t)bg * 1024 + hh * 256 + o] = acc[hh] + fb;
  }
}

extern "C" void kernel_launch(void* const* d_in, const int* in_sizes, int n_in,
                              void* d_out, int out_size, void* d_ws, size_t ws_size,
                              hipStream_t stream) {
  const int* conn = (const int*)d_in[0];
  const int* mask = (const int*)d_in[1];
  const float* emb = (const float*)d_in[2];
  const float* qkv_w = (const float*)d_in[3];
  const float* qkv_b = (const float*)d_in[4];
  const float* proj_w = (const float*)d_in[5];
  const float* proj_b = (const float*)d_in[6];
  const float* ln1g = (const float*)d_in[7];
  const float* ln1b = (const float*)d_in[8];
  const float* ln2g = (const float*)d_in[9];
  const float* ln2b = (const float*)d_in[10];
  const float* fc_w = (const float*)d_in[11];
  const float* fc_b = (const float*)d_in[12];
  float* out = (float*)d_out;

  // ---- ws layout (fixed part) ----
  size_t off = 0;
  auto alloc = [&](size_t bytes) {
    void* p = (char*)d_ws + off;
    off += (bytes + 255) & ~(size_t)255;
    return p;
  };
  unsigned short* w_qkv = (unsigned short*)alloc((size_t)1536 * 512 * 2);
  unsigned short* w_proj = (unsigned short*)alloc((size_t)512 * 512 * 2);
  unsigned short* w_fc = (unsigned short*)alloc((size_t)256 * 512 * 2);
  float* am = (float*)alloc((size_t)1024 * 400 * 4);
  const size_t fixed = off;

  // ---- adaptive chunk size: largest CB with footprint <= ws_size ----
  int CB = 1024;
  while (CB > 32) {
    size_t need = fixed + (size_t)CB * 100 * 512 * 2 + (size_t)CB * 100 * 1536 * 2 + 1024;
    if (need <= ws_size) break;
    CB >>= 1;
  }
  unsigned short* xn = (unsigned short*)alloc((size_t)CB * 100 * 512 * 2);    // aliased as y
  unsigned short* qkvb = (unsigned short*)alloc((size_t)CB * 100 * 1536 * 2); // aliased as pout

  k_cvt<<<(786432 + 255) / 256, 256, 0, stream>>>(qkv_w, w_qkv, 786432);
  k_cvt<<<(262144 + 255) / 256, 256, 0, stream>>>(proj_w, w_proj, 262144);
  k_cvt<<<(131072 + 255) / 256, 256, 0, stream>>>(fc_w, w_fc, 131072);

  const int mt = CB * 100 / 128;  // CB multiple of 32 -> exact
  for (int b0 = 0; b0 < 1024; b0 += CB) {
    k_gather_ln<<<CB * 25, 256, 0, stream>>>(conn, emb, ln1g, ln1b, xn, b0 * 100);
    k_gemm<<<dim3(12, mt), 256, 0, stream>>>(xn, w_qkv, qkv_b, qkvb, 1536, 512);
    k_attn<<<CB * 4, 512, 0, stream>>>(qkvb, mask, xn /*y*/, am, b0);
    k_gemm<<<dim3(4, mt), 256, 0, stream>>>(xn /*y*/, w_proj, proj_b, qkvb /*pout*/, 512, 512);
    k_final<<<CB, 256, 0, stream>>>(am, qkvb /*pout*/, ln2g, ln2b, w_fc, fc_b, out, b0);
  }
}